// Round 14
// baseline (72.144 us; speedup 1.0000x reference)
//
#include <hip/hip_runtime.h>

// WaveletProcessor: 4x [Conv1d(64,64,k) -> ReLU -> Conv1d(64,64,1)], softmax-weighted sum.
// Device buffers are float32. Compute: bf16 MFMA (16x16x32 conv1, 16x16x16 conv2), fp32 accum.
// Round 14: r10's barrier-free free-running structure at nt=2 (64x32 wave tile) with
// split-phase weight loads (W0=frags0-3 current, W1=frags4-7 loaded early-period,
// frags0-3 of S+1 loaded mid-period) -> 32 weight regs instead of 64 -> ~155 total regs
// -> 3 waves/SIMD, 3 blocks/CU, 12 free-running waves. L1 shares the slice stream.

constexpr int Bn = 32, Ln = 8192;
constexpr int NT = 128;          // length-tile per workgroup (4 waves x 32)
constexpr int HALO = 4;
constexpr int XROWS = NT + 2 * HALO;   // 136
constexpr int RS = 72;           // LDS row stride in ushorts (144B -> 2-way alias, free)
constexpr int NSLICE = 24;       // 4+4+6+10 weight slices of 8KB (4096 ushorts)

// slice descriptors: branch and dk (-1 = F2/conv2 slice)
constexpr int BRS[NSLICE] = {0,0,0,0, 1,1,1,1, 2,2,2,2,2,2, 3,3,3,3,3,3,3,3,3,3};
constexpr int DKS[NSLICE] = {0,1,2,-1, 0,1,2,-1, 0,1,2,3,4,-1, 0,1,2,3,4,5,6,7,8,-1};
constexpr int PPB[4] = {1, 1, 2, 4};

using bf16x8 = __attribute__((ext_vector_type(8))) __bf16;
using f32x4  = __attribute__((ext_vector_type(4))) float;
using u16x8  = __attribute__((ext_vector_type(8))) unsigned short;
using u16x4  = __attribute__((ext_vector_type(4))) unsigned short;
using s16x4  = __attribute__((ext_vector_type(4))) short;

struct Ptrs {
    const float* x;
    const float* rw;
    const float* w1[4];
    const float* b1[4];
    const float* w2[4];
    const float* b2[4];
};

__device__ __forceinline__ unsigned short f2bf(float f) {
    __bf16 h = (__bf16)f;
    return __builtin_bit_cast(unsigned short, h);
}

#if defined(__has_builtin)
#  if __has_builtin(__builtin_amdgcn_mfma_f32_16x16x16bf16_1k)
#    define HAVE_MFMA16 1
#  endif
#endif

__device__ __forceinline__ void mfma16(f32x4& c, u16x4 a, u16x4 b) {
#ifdef HAVE_MFMA16
    c = __builtin_amdgcn_mfma_f32_16x16x16bf16_1k(
            __builtin_bit_cast(s16x4, a), __builtin_bit_cast(s16x4, b), c, 0, 0, 0);
#else
    asm("v_mfma_f32_16x16x16_bf16 %0, %1, %2, %0" : "+v"(c) : "v"(a), "v"(b));
#endif
}

// ---------------- prep: softmax + weights into slice-ordered fragments ----------------
// d_ws: [0..3] float softmax w; [4..67] float fused bias (sum_i w_i*b2_i);
// at byte 512: 24 slices x 4096 ushorts (8KB). Every slice = 8 chunks of 512 ushorts,
// lane reads chunk c at c*512 + lane*8 (16B, coalesced 1KB per chunk per wave).
//   F1 slice (br,dk): chunk c = ks*4+mt; elem lane*8+j;
//     co=mt*16+(lane&15), ci=ks*32+(lane>>4)*8+j; val = W1[co][ci][dk].
//   F2 slice (br): chunk c holds frag PAIR f=2c,2c+1 (f=kb*4+mt); elem = lane*8 + h*4 + j
//     (h=f&1); co=mt*16+(lane&15), ci=kb*16+(lane>>4)*4+j; val = w[br]*W2[co][ci].
__global__ void prep_kernel(Ptrs p, unsigned short* __restrict__ frag, float* __restrict__ hdr) {
    int tid = threadIdx.x;
    float v0 = p.rw[0], v1 = p.rw[1], v2 = p.rw[2], v3 = p.rw[3];
    float m = fmaxf(fmaxf(v0, v1), fmaxf(v2, v3));
    float e0 = expf(v0 - m), e1 = expf(v1 - m), e2 = expf(v2 - m), e3 = expf(v3 - m);
    float s = e0 + e1 + e2 + e3;
    float w[4] = {e0 / s, e1 / s, e2 / s, e3 / s};

    if (blockIdx.x == 0) {
        if (tid < 4) hdr[tid] = w[tid];
        if (tid < 64) {
            float fb = 0.f;
            #pragma unroll
            for (int i = 0; i < 4; i++) fb += w[i] * p.b2[i][tid];
            hdr[4 + tid] = fb;
        }
    }

    const int kk[4] = {3, 3, 5, 9};
    const int sbase[4] = {0, 4, 8, 14};

    for (int idx = blockIdx.x * blockDim.x + tid; idx < NSLICE * 4096; idx += gridDim.x * blockDim.x) {
        int sl = idx >> 12;
        int e = idx & 4095;
        int br = 3;
        #pragma unroll
        for (int i = 2; i >= 0; i--) if (sl < sbase[i + 1]) br = i;
        int local = sl - sbase[br];
        unsigned short val;
        if (local < kk[br]) {       // F1 slice, dk = local
            int blk = e >> 9;       // chunk = ks*4 + mt
            int ks = blk >> 2, mt = blk & 3;
            int sub = e & 511;
            int lane = sub >> 3, j = sub & 7;
            int co = mt * 16 + (lane & 15);
            int ci = ks * 32 + (lane >> 4) * 8 + j;
            val = f2bf(p.w1[br][(co * 64 + ci) * kk[br] + local]);
        } else {                    // F2 slice, chunk-paired layout
            int c = e >> 9;
            int sub = e & 511;
            int lane = sub >> 3;
            int rest = sub & 7;
            int h = rest >> 2, j = rest & 3;
            int f = c * 2 + h;      // f = kb*4 + mt
            int kb = f >> 2, mt = f & 3;
            int co = mt * 16 + (lane & 15);
            int ci = kb * 16 + (lane >> 4) * 4 + j;
            val = f2bf(w[br] * p.w2[br][co * 64 + ci]);
        }
        frag[idx] = val;
    }
}

// ---------------- main kernel: 24 free-running periods, split-phase weight loads --------
// Invariant at period S entry: W0 holds frags 0-3 of slice S.
template <int S>
__device__ __forceinline__ void period(const unsigned short* __restrict__ frag,
                                       const unsigned short* xs,
                                       const float* b1l,
                                       int lane, int wl0,
                                       f32x4 (&acc)[4][2], f32x4 (&fused)[4][2],
                                       bf16x8 (&W0)[4], bf16x8 (&W1)[4]) {
    constexpr int br = BRS[S];
    constexpr int dk = DKS[S];
    int col = lane & 15, kg = lane >> 4;

    // issue late-half loads of current slice (consumed this period's 2nd half)
    {
        const unsigned short* bc = frag + (size_t)S * 4096 + lane * 8;
        #pragma unroll
        for (int c = 0; c < 4; c++)
            W1[c] = __builtin_bit_cast(bf16x8, *(const u16x8*)(bc + (size_t)(4 + c) * 512));
    }

    if constexpr (dk >= 0) {
        // ---- conv1 F1 slice ----
        if constexpr (dk == 0) {
            #pragma unroll
            for (int mt = 0; mt < 4; mt++)
                #pragma unroll
                for (int nt = 0; nt < 2; nt++)
                    acc[mt][nt] = f32x4{0.f, 0.f, 0.f, 0.f};
        }
        constexpr int PP = PPB[br];
        // first half: ks=0 with W0
        {
            bf16x8 bfr[2];
            #pragma unroll
            for (int nt = 0; nt < 2; nt++) {
                int row = wl0 + nt * 16 + col + (HALO - PP) + dk;
                bfr[nt] = __builtin_bit_cast(bf16x8, *(const u16x8*)&xs[row * RS + kg * 8]);
            }
            __builtin_amdgcn_s_setprio(1);
            #pragma unroll
            for (int mt = 0; mt < 4; mt++)
                #pragma unroll
                for (int nt = 0; nt < 2; nt++)
                    acc[mt][nt] = __builtin_amdgcn_mfma_f32_16x16x32_bf16(W0[mt], bfr[nt], acc[mt][nt], 0, 0, 0);
            __builtin_amdgcn_s_setprio(0);
        }
        // mid: issue early-half loads of next slice into W0
        if constexpr (S + 1 < NSLICE) {
            const unsigned short* bn = frag + (size_t)(S + 1) * 4096 + lane * 8;
            #pragma unroll
            for (int c = 0; c < 4; c++)
                W0[c] = __builtin_bit_cast(bf16x8, *(const u16x8*)(bn + (size_t)c * 512));
        }
        // second half: ks=1 with W1
        {
            bf16x8 bfr[2];
            #pragma unroll
            for (int nt = 0; nt < 2; nt++) {
                int row = wl0 + nt * 16 + col + (HALO - PP) + dk;
                bfr[nt] = __builtin_bit_cast(bf16x8, *(const u16x8*)&xs[row * RS + 32 + kg * 8]);
            }
            __builtin_amdgcn_s_setprio(1);
            #pragma unroll
            for (int mt = 0; mt < 4; mt++)
                #pragma unroll
                for (int nt = 0; nt < 2; nt++)
                    acc[mt][nt] = __builtin_amdgcn_mfma_f32_16x16x32_bf16(W1[mt], bfr[nt], acc[mt][nt], 0, 0, 0);
            __builtin_amdgcn_s_setprio(0);
        }
    } else {
        // ---- conv2 F2 slice: ReLU(acc + b1) repacked in-lane is the 16x16x16 B-frag ----
        const float* bb = b1l + br * 64;
        f32x4 bv[4];
        #pragma unroll
        for (int mt = 0; mt < 4; mt++) bv[mt] = *(const f32x4*)&bb[mt * 16 + kg * 4];
        // first half: kb=0,1 with W0 (frags 0-7 -> W0[0..3])
        #pragma unroll
        for (int kb = 0; kb < 2; kb++) {
            u16x4 hb[2];
            #pragma unroll
            for (int nt = 0; nt < 2; nt++) {
                u16x4 h;
                #pragma unroll
                for (int r = 0; r < 4; r++) h[r] = f2bf(fmaxf(acc[kb][nt][r] + bv[kb][r], 0.f));
                hb[nt] = h;
            }
            __builtin_amdgcn_s_setprio(1);
            #pragma unroll
            for (int mt2 = 0; mt2 < 4; mt2++) {
                int f = kb * 4 + mt2;
                u16x8 u = __builtin_bit_cast(u16x8, W0[f >> 1]);
                int h4 = (f & 1) * 4;
                u16x4 afr = {u[h4], u[h4 + 1], u[h4 + 2], u[h4 + 3]};
                #pragma unroll
                for (int nt = 0; nt < 2; nt++)
                    mfma16(fused[mt2][nt], afr, hb[nt]);
            }
            __builtin_amdgcn_s_setprio(0);
        }
        // mid: issue early-half loads of next slice into W0
        if constexpr (S + 1 < NSLICE) {
            const unsigned short* bn = frag + (size_t)(S + 1) * 4096 + lane * 8;
            #pragma unroll
            for (int c = 0; c < 4; c++)
                W0[c] = __builtin_bit_cast(bf16x8, *(const u16x8*)(bn + (size_t)c * 512));
        }
        // second half: kb=2,3 with W1 (frags 8-15 -> W1[0..3])
        #pragma unroll
        for (int kb = 2; kb < 4; kb++) {
            u16x4 hb[2];
            #pragma unroll
            for (int nt = 0; nt < 2; nt++) {
                u16x4 h;
                #pragma unroll
                for (int r = 0; r < 4; r++) h[r] = f2bf(fmaxf(acc[kb][nt][r] + bv[kb][r], 0.f));
                hb[nt] = h;
            }
            __builtin_amdgcn_s_setprio(1);
            #pragma unroll
            for (int mt2 = 0; mt2 < 4; mt2++) {
                int f = kb * 4 + mt2;
                u16x8 u = __builtin_bit_cast(u16x8, W1[(f >> 1) - 4]);
                int h4 = (f & 1) * 4;
                u16x4 afr = {u[h4], u[h4 + 1], u[h4 + 2], u[h4 + 3]};
                #pragma unroll
                for (int nt = 0; nt < 2; nt++)
                    mfma16(fused[mt2][nt], afr, hb[nt]);
            }
            __builtin_amdgcn_s_setprio(0);
        }
    }
}

template <int S>
__device__ __forceinline__ void chain(const unsigned short* __restrict__ frag,
                                      const unsigned short* xs,
                                      const float* b1l, int lane, int wl0,
                                      f32x4 (&acc)[4][2], f32x4 (&fused)[4][2],
                                      bf16x8 (&W0)[4], bf16x8 (&W1)[4]) {
    period<S>(frag, xs, b1l, lane, wl0, acc, fused, W0, W1);
    if constexpr (S + 1 < NSLICE)
        chain<S + 1>(frag, xs, b1l, lane, wl0, acc, fused, W0, W1);
}

__global__ __launch_bounds__(256, 3) void wavelet_main(Ptrs p,
                                                       const unsigned short* __restrict__ frag,
                                                       const float* __restrict__ hdr,
                                                       float* __restrict__ out) {
    __shared__ unsigned short xs[XROWS * RS];   // 19584 B
    __shared__ float b1l[4 * 64];               // 1024 B
    __shared__ float fbl[64];                   // 256 B  -> ~20.9 KB total

    int tid = threadIdx.x;
    int b = blockIdx.x >> 6;           // 64 tiles per batch
    int t0 = (blockIdx.x & 63) * NT;

    // stage x tile (+halo) into LDS as bf16, zero-padded at batch edges
    {
        int c0 = (tid & 7) * 8;
        int rbase = tid >> 3;          // 0..31
        #pragma unroll
        for (int it = 0; it < 5; it++) {
            int rr = it * 32 + rbase;
            if (rr < XROWS) {
                int l = t0 + rr - HALO;
                u16x8 v = {0, 0, 0, 0, 0, 0, 0, 0};
                if (l >= 0 && l < Ln) {
                    const float* src = &p.x[((size_t)b * Ln + l) * 64 + c0];
                    f32x4 a0 = *(const f32x4*)src;
                    f32x4 a1 = *(const f32x4*)(src + 4);
                    #pragma unroll
                    for (int r = 0; r < 4; r++) { v[r] = f2bf(a0[r]); v[4 + r] = f2bf(a1[r]); }
                }
                *(u16x8*)&xs[rr * RS + c0] = v;
            }
        }
    }
    b1l[tid] = p.b1[tid >> 6][tid & 63];
    if (tid < 64) fbl[tid] = hdr[4 + tid];

    int lane = tid & 63;
    int wl0 = (tid >> 6) * 32;   // each wave owns a 32-wide L-chunk
    int kg = lane >> 4;

    // pre-load slice 0's early-half weight fragments (overlaps xs staging latency)
    bf16x8 W0[4], W1[4];
    {
        const unsigned short* b0 = frag + lane * 8;
        #pragma unroll
        for (int c = 0; c < 4; c++)
            W0[c] = __builtin_bit_cast(bf16x8, *(const u16x8*)(b0 + (size_t)c * 512));
    }

    f32x4 acc[4][2];
    f32x4 fused[4][2];
    #pragma unroll
    for (int mt = 0; mt < 4; mt++)
        #pragma unroll
        for (int nt = 0; nt < 2; nt++)
            fused[mt][nt] = f32x4{0.f, 0.f, 0.f, 0.f};

    __syncthreads();   // xs + biases ready — the ONLY barrier

    chain<0>(frag, xs, b1l, lane, wl0, acc, fused, W0, W1);

#ifndef HAVE_MFMA16
    asm volatile("s_nop 7\ns_nop 7");   // MFMA->VALU hazard guard for asm path
#endif

    // epilogue: add fused bias; nt-outer so each l's 256B line is written back-to-back
    int col = lane & 15;
    f32x4 fb[4];
    #pragma unroll
    for (int mt = 0; mt < 4; mt++) fb[mt] = *(const f32x4*)&fbl[mt * 16 + kg * 4];
    #pragma unroll
    for (int nt = 0; nt < 2; nt++) {
        int l = t0 + wl0 + nt * 16 + col;
        #pragma unroll
        for (int mt = 0; mt < 4; mt++) {
            f32x4 v;
            #pragma unroll
            for (int r = 0; r < 4; r++) v[r] = fused[mt][nt][r] + fb[mt][r];
            *(f32x4*)&out[((size_t)b * Ln + l) * 64 + mt * 16 + kg * 4] = v;
        }
    }
}

extern "C" void kernel_launch(void* const* d_in, const int* in_sizes, int n_in,
                              void* d_out, int out_size, void* d_ws, size_t ws_size,
                              hipStream_t stream) {
    Ptrs p;
    p.x  = (const float*)d_in[0];
    p.rw = (const float*)d_in[1];
    for (int i = 0; i < 4; i++) {
        p.w1[i] = (const float*)d_in[2 + 4 * i];
        p.b1[i] = (const float*)d_in[3 + 4 * i];
        p.w2[i] = (const float*)d_in[4 + 4 * i];
        p.b2[i] = (const float*)d_in[5 + 4 * i];
    }
    float* hdr = (float*)d_ws;
    unsigned short* frag = (unsigned short*)((char*)d_ws + 512);

    hipLaunchKernelGGL(prep_kernel, dim3(96), dim3(256), 0, stream, p, frag, hdr);
    hipLaunchKernelGGL(wavelet_main, dim3(Bn * (Ln / NT)), dim3(256), 0, stream, p, frag, hdr,
                       (float*)d_out);
}

// Round 15
// 61.817 us; speedup vs baseline: 1.1670x; 1.1670x over previous
//
#include <hip/hip_runtime.h>

// WaveletProcessor: 4x [Conv1d(64,64,k) -> ReLU -> Conv1d(64,64,1)], softmax-weighted sum.
// Device buffers are float32. Compute: bf16 MFMA (16x16x32 conv1, 16x16x16 conv2), fp32 accum.
// FINAL (revert to round-10 optimum, 61.7us): barrier-free free-running waves; weight
// fragments read directly global->VGPR from slice-ordered L2-resident stream, register
// double-buffered one period ahead; LDS holds only the x tile + biases; one barrier total.
// Measured bracket: 64 cols/wave @ 2 waves/SIMD is the optimum of the
// (occupancy x weight-traffic) tradeoff (r6: 128c/1w=176us, r14: 32c/3w=72us, this: 61.7us).

constexpr int Bn = 32, Ln = 8192;
constexpr int NT = 256;          // length-tile per workgroup (4 waves x 64)
constexpr int HALO = 4;
constexpr int XROWS = NT + 2 * HALO;   // 264
constexpr int RS = 72;           // LDS row stride in ushorts (144B -> 2-way alias, free)
constexpr int NSLICE = 24;       // 4+4+6+10 weight slices of 8KB (4096 ushorts)

// slice descriptors: branch and dk (-1 = F2/conv2 slice)
constexpr int BRS[NSLICE] = {0,0,0,0, 1,1,1,1, 2,2,2,2,2,2, 3,3,3,3,3,3,3,3,3,3};
constexpr int DKS[NSLICE] = {0,1,2,-1, 0,1,2,-1, 0,1,2,3,4,-1, 0,1,2,3,4,5,6,7,8,-1};
constexpr int PPB[4] = {1, 1, 2, 4};

using bf16x8 = __attribute__((ext_vector_type(8))) __bf16;
using f32x4  = __attribute__((ext_vector_type(4))) float;
using u16x8  = __attribute__((ext_vector_type(8))) unsigned short;
using u16x4  = __attribute__((ext_vector_type(4))) unsigned short;
using s16x4  = __attribute__((ext_vector_type(4))) short;

struct Ptrs {
    const float* x;
    const float* rw;
    const float* w1[4];
    const float* b1[4];
    const float* w2[4];
    const float* b2[4];
};

__device__ __forceinline__ unsigned short f2bf(float f) {
    __bf16 h = (__bf16)f;
    return __builtin_bit_cast(unsigned short, h);
}

#if defined(__has_builtin)
#  if __has_builtin(__builtin_amdgcn_mfma_f32_16x16x16bf16_1k)
#    define HAVE_MFMA16 1
#  endif
#endif

__device__ __forceinline__ void mfma16(f32x4& c, u16x4 a, u16x4 b) {
#ifdef HAVE_MFMA16
    c = __builtin_amdgcn_mfma_f32_16x16x16bf16_1k(
            __builtin_bit_cast(s16x4, a), __builtin_bit_cast(s16x4, b), c, 0, 0, 0);
#else
    asm("v_mfma_f32_16x16x16_bf16 %0, %1, %2, %0" : "+v"(c) : "v"(a), "v"(b));
#endif
}

// ---------------- prep: softmax + weights into slice-ordered fragments ----------------
// d_ws: [0..3] float softmax w; [4..67] float fused bias (sum_i w_i*b2_i);
// at byte 512: 24 slices x 4096 ushorts (8KB). Every slice = 8 chunks of 512 ushorts,
// lane reads chunk c at c*512 + lane*8 (16B, coalesced 1KB per chunk per wave).
//   F1 slice (br,dk): chunk c = ks*4+mt; elem lane*8+j;
//     co=mt*16+(lane&15), ci=ks*32+(lane>>4)*8+j; val = W1[co][ci][dk].
//   F2 slice (br): chunk c holds frag PAIR f=2c,2c+1 (f=kb*4+mt); elem = lane*8 + h*4 + j
//     (h=f&1); co=mt*16+(lane&15), ci=kb*16+(lane>>4)*4+j; val = w[br]*W2[co][ci].
__global__ void prep_kernel(Ptrs p, unsigned short* __restrict__ frag, float* __restrict__ hdr) {
    int tid = threadIdx.x;
    float v0 = p.rw[0], v1 = p.rw[1], v2 = p.rw[2], v3 = p.rw[3];
    float m = fmaxf(fmaxf(v0, v1), fmaxf(v2, v3));
    float e0 = expf(v0 - m), e1 = expf(v1 - m), e2 = expf(v2 - m), e3 = expf(v3 - m);
    float s = e0 + e1 + e2 + e3;
    float w[4] = {e0 / s, e1 / s, e2 / s, e3 / s};

    if (blockIdx.x == 0) {
        if (tid < 4) hdr[tid] = w[tid];
        if (tid < 64) {
            float fb = 0.f;
            #pragma unroll
            for (int i = 0; i < 4; i++) fb += w[i] * p.b2[i][tid];
            hdr[4 + tid] = fb;
        }
    }

    const int kk[4] = {3, 3, 5, 9};
    const int sbase[4] = {0, 4, 8, 14};

    for (int idx = blockIdx.x * blockDim.x + tid; idx < NSLICE * 4096; idx += gridDim.x * blockDim.x) {
        int sl = idx >> 12;
        int e = idx & 4095;
        int br = 3;
        #pragma unroll
        for (int i = 2; i >= 0; i--) if (sl < sbase[i + 1]) br = i;
        int local = sl - sbase[br];
        unsigned short val;
        if (local < kk[br]) {       // F1 slice, dk = local
            int blk = e >> 9;       // chunk = ks*4 + mt
            int ks = blk >> 2, mt = blk & 3;
            int sub = e & 511;
            int lane = sub >> 3, j = sub & 7;
            int co = mt * 16 + (lane & 15);
            int ci = ks * 32 + (lane >> 4) * 8 + j;
            val = f2bf(p.w1[br][(co * 64 + ci) * kk[br] + local]);
        } else {                    // F2 slice, chunk-paired layout
            int c = e >> 9;
            int sub = e & 511;
            int lane = sub >> 3;
            int rest = sub & 7;
            int h = rest >> 2, j = rest & 3;
            int f = c * 2 + h;      // f = kb*4 + mt
            int kb = f >> 2, mt = f & 3;
            int co = mt * 16 + (lane & 15);
            int ci = kb * 16 + (lane >> 4) * 4 + j;
            val = f2bf(w[br] * p.w2[br][co * 64 + ci]);
        }
        frag[idx] = val;
    }
}

// ---------------- main kernel: one uniform period per slice, no barriers ----------------
template <int S>
__device__ __forceinline__ void period(const unsigned short* __restrict__ frag,
                                       const unsigned short* xs,
                                       const float* b1l,
                                       int lane, int wl0,
                                       f32x4 (&acc)[4][4], f32x4 (&fused)[4][4],
                                       bf16x8 (&cur)[8], bf16x8 (&nxt)[8]) {
    // issue next slice's 8 weight fragments global->reg (L2-hit, consumed next period)
    if constexpr (S + 1 < NSLICE) {
        const unsigned short* nb = frag + (size_t)(S + 1) * 4096 + lane * 8;
        #pragma unroll
        for (int c = 0; c < 8; c++)
            nxt[c] = __builtin_bit_cast(bf16x8, *(const u16x8*)(nb + c * 512));
    }

    constexpr int br = BRS[S];
    constexpr int dk = DKS[S];
    int col = lane & 15, kg = lane >> 4;

    if constexpr (dk >= 0) {
        // conv1 F1 slice
        if constexpr (dk == 0) {
            #pragma unroll
            for (int mt = 0; mt < 4; mt++)
                #pragma unroll
                for (int nt = 0; nt < 4; nt++)
                    acc[mt][nt] = f32x4{0.f, 0.f, 0.f, 0.f};
        }
        constexpr int PP = PPB[br];
        #pragma unroll
        for (int ks = 0; ks < 2; ks++) {
            bf16x8 bfr[4];
            #pragma unroll
            for (int nt = 0; nt < 4; nt++) {
                int row = wl0 + nt * 16 + col + (HALO - PP) + dk;
                bfr[nt] = __builtin_bit_cast(bf16x8, *(const u16x8*)&xs[row * RS + ks * 32 + kg * 8]);
            }
            __builtin_amdgcn_s_setprio(1);
            #pragma unroll
            for (int mt = 0; mt < 4; mt++)
                #pragma unroll
                for (int nt = 0; nt < 4; nt++)
                    acc[mt][nt] = __builtin_amdgcn_mfma_f32_16x16x32_bf16(cur[ks * 4 + mt], bfr[nt], acc[mt][nt], 0, 0, 0);
            __builtin_amdgcn_s_setprio(0);
        }
    } else {
        // conv2 F2 slice: ReLU(acc + b1) repacked in-lane is the 16x16x16 B-fragment
        const float* bb = b1l + br * 64;
        f32x4 bv[4];
        #pragma unroll
        for (int mt = 0; mt < 4; mt++) bv[mt] = *(const f32x4*)&bb[mt * 16 + kg * 4];
        #pragma unroll
        for (int kb = 0; kb < 4; kb++) {
            u16x4 hb[4];
            #pragma unroll
            for (int nt = 0; nt < 4; nt++) {
                u16x4 h;
                #pragma unroll
                for (int r = 0; r < 4; r++) h[r] = f2bf(fmaxf(acc[kb][nt][r] + bv[kb][r], 0.f));
                hb[nt] = h;
            }
            __builtin_amdgcn_s_setprio(1);
            #pragma unroll
            for (int mt2 = 0; mt2 < 4; mt2++) {
                int f = kb * 4 + mt2;
                u16x8 u = __builtin_bit_cast(u16x8, cur[f >> 1]);
                int h4 = (f & 1) * 4;
                u16x4 afr = {u[h4], u[h4 + 1], u[h4 + 2], u[h4 + 3]};
                #pragma unroll
                for (int nt = 0; nt < 4; nt++)
                    mfma16(fused[mt2][nt], afr, hb[nt]);
            }
            __builtin_amdgcn_s_setprio(0);
        }
    }
}

template <int S>
__device__ __forceinline__ void chain(const unsigned short* __restrict__ frag,
                                      const unsigned short* xs,
                                      const float* b1l, int lane, int wl0,
                                      f32x4 (&acc)[4][4], f32x4 (&fused)[4][4],
                                      bf16x8 (&A)[8], bf16x8 (&B)[8]) {
    if constexpr (S & 1) period<S>(frag, xs, b1l, lane, wl0, acc, fused, B, A);
    else                 period<S>(frag, xs, b1l, lane, wl0, acc, fused, A, B);
    if constexpr (S + 1 < NSLICE)
        chain<S + 1>(frag, xs, b1l, lane, wl0, acc, fused, A, B);
}

__global__ __launch_bounds__(256, 2) void wavelet_main(Ptrs p,
                                                       const unsigned short* __restrict__ frag,
                                                       const float* __restrict__ hdr,
                                                       float* __restrict__ out) {
    __shared__ unsigned short xs[XROWS * RS];   // 38016 B
    __shared__ float b1l[4 * 64];               // conv1 biases
    __shared__ float fbl[64];                   // fused bias sum_i w_i*b2_i

    int tid = threadIdx.x;
    int b = blockIdx.x >> 5;
    int t0 = (blockIdx.x & 31) * NT;

    // stage x tile (+halo) into LDS as bf16, zero-padded at batch edges
    {
        int c0 = (tid & 7) * 8;
        int rbase = tid >> 3;
        #pragma unroll
        for (int it = 0; it < 9; it++) {
            int rr = it * 32 + rbase;
            if (rr < XROWS) {
                int l = t0 + rr - HALO;
                u16x8 v = {0, 0, 0, 0, 0, 0, 0, 0};
                if (l >= 0 && l < Ln) {
                    const float* src = &p.x[((size_t)b * Ln + l) * 64 + c0];
                    f32x4 a0 = *(const f32x4*)src;
                    f32x4 a1 = *(const f32x4*)(src + 4);
                    #pragma unroll
                    for (int r = 0; r < 4; r++) { v[r] = f2bf(a0[r]); v[4 + r] = f2bf(a1[r]); }
                }
                *(u16x8*)&xs[rr * RS + c0] = v;
            }
        }
    }
    b1l[tid] = p.b1[tid >> 6][tid & 63];
    if (tid < 64) fbl[tid] = hdr[4 + tid];

    int lane = tid & 63;
    int wl0 = (tid >> 6) * 64;
    int kg = lane >> 4;

    // pre-load slice 0's weight fragments into registers (overlaps xs staging latency)
    bf16x8 A[8], B[8];
    {
        const unsigned short* b0 = frag + lane * 8;
        #pragma unroll
        for (int c = 0; c < 8; c++)
            A[c] = __builtin_bit_cast(bf16x8, *(const u16x8*)(b0 + c * 512));
    }

    f32x4 acc[4][4];
    f32x4 fused[4][4];
    #pragma unroll
    for (int mt = 0; mt < 4; mt++)
        #pragma unroll
        for (int nt = 0; nt < 4; nt++)
            fused[mt][nt] = f32x4{0.f, 0.f, 0.f, 0.f};

    __syncthreads();   // xs + biases ready — the ONLY barrier

    chain<0>(frag, xs, b1l, lane, wl0, acc, fused, A, B);

#ifndef HAVE_MFMA16
    asm volatile("s_nop 7\ns_nop 7");   // MFMA->VALU hazard guard for asm path
#endif

    // epilogue: add fused bias; nt-outer so each l's 256B line is written back-to-back
    int col = lane & 15;
    f32x4 fb[4];
    #pragma unroll
    for (int mt = 0; mt < 4; mt++) fb[mt] = *(const f32x4*)&fbl[mt * 16 + kg * 4];
    #pragma unroll
    for (int nt = 0; nt < 4; nt++) {
        int l = t0 + wl0 + nt * 16 + col;
        #pragma unroll
        for (int mt = 0; mt < 4; mt++) {
            f32x4 v;
            #pragma unroll
            for (int r = 0; r < 4; r++) v[r] = fused[mt][nt][r] + fb[mt][r];
            *(f32x4*)&out[((size_t)b * Ln + l) * 64 + mt * 16 + kg * 4] = v;
        }
    }
}

extern "C" void kernel_launch(void* const* d_in, const int* in_sizes, int n_in,
                              void* d_out, int out_size, void* d_ws, size_t ws_size,
                              hipStream_t stream) {
    Ptrs p;
    p.x  = (const float*)d_in[0];
    p.rw = (const float*)d_in[1];
    for (int i = 0; i < 4; i++) {
        p.w1[i] = (const float*)d_in[2 + 4 * i];
        p.b1[i] = (const float*)d_in[3 + 4 * i];
        p.w2[i] = (const float*)d_in[4 + 4 * i];
        p.b2[i] = (const float*)d_in[5 + 4 * i];
    }
    float* hdr = (float*)d_ws;
    unsigned short* frag = (unsigned short*)((char*)d_ws + 512);

    hipLaunchKernelGGL(prep_kernel, dim3(96), dim3(256), 0, stream, p, frag, hdr);
    hipLaunchKernelGGL(wavelet_main, dim3(Bn * (Ln / NT)), dim3(256), 0, stream, p, frag, hdr,
                       (float*)d_out);
}